// Round 7
// baseline (117.694 us; speedup 1.0000x reference)
//
#include <hip/hip_runtime.h>
#include <math.h>

// SANet attention: MFMA flash, LDS-staged K/V (xor-swizzled), 64 q-rows/wave,
// split-K(8), f16 partials. b=4, c=64, HW=4096, fp32 in/out.
// out[b,0:64,:] = content ; out[b,64:128,q] = sum_k Fst[:,k] softmax_k(Fc[:,q].Fs[:,k])
//
// R6 post-mortem: attn 44us, VALU 49%, LDS ~75%; ~45us of dur_us is the
// harness's 268MB ws-poison fill (uncontrollable). R7: 4 Q-groups per wave
// share every K/V fragment read -> wave-tile visits halve (32768->16384),
// halving LDS frag traffic + per-tile VALU overhead. SPLITS=8 keeps grid=512
// (2 blocks/CU). Qt re-added to prep (pre-scaled by log2e) -> Q preamble is
// 8 b128 loads. Ps: 2 alternating 16-row sets per wave.
//
// mfma_f32_16x16x32_f16: A[m=lane&15][k=quad*8+j], B[k=quad*8+j][n=lane&15],
// D[m=quad*4+reg][n=lane&15]  (quad = lane>>4).
// S-mfma computes S^T tile (m=k_key, n=q); PV computes O^T (m=c, n=q).

#define Bb 4
#define Cc 64
#define HWs 4096
#define SPLITS 8
#define TPS 8                   // tiles per split: 512 keys / 64
#define RLOG2E 1.44269504088896340736f

typedef _Float16 half8 __attribute__((ext_vector_type(8)));
typedef _Float16 half4 __attribute__((ext_vector_type(4)));
typedef float floatx4 __attribute__((ext_vector_type(4)));

// ---- prep: content copy + Vt convert + Kt transpose + Qt transpose(scaled) ----
__global__ __launch_bounds__(256) void prep_k(const float* __restrict__ content,
                                              const float* __restrict__ Fc,
                                              const float* __restrict__ Fs,
                                              const float* __restrict__ Fst,
                                              float* __restrict__ out,
                                              _Float16* __restrict__ Qt,
                                              _Float16* __restrict__ Kt,
                                              _Float16* __restrict__ Vt) {
    const int bid = blockIdx.x;
    const int t = threadIdx.x;
    const int sect = bid >> 10;
    if (sect == 0) {
        // content copy (float4) + V f16 convert (same linear layout)
        int i4 = bid * 256 + t;                       // 0..262143
        const float4* c4 = (const float4*)content;
        const float4* v4 = (const float4*)Fst;
        float4* o4 = (float4*)out;
        int b = i4 >> 16, rem = i4 & 65535;
        o4[(size_t)b * 131072 + rem] = c4[i4];        // out batch stride 2*64*4096 f32
        float4 v = v4[i4];
        half4 h;
        h[0] = (_Float16)v.x; h[1] = (_Float16)v.y;
        h[2] = (_Float16)v.z; h[3] = (_Float16)v.w;
        *(half4*)(Vt + (size_t)i4 * 4) = h;
    } else {
        // transpose+convert one 16hw x 64c tile: Fs->Kt (sect1), Fc->Qt*log2e (sect2)
        __shared__ _Float16 T[16][72];
        int e = bid & 1023;                           // 0..1023
        int b = e >> 8;
        int hw0 = (e & 255) * 16;
        const float* src = (sect == 1) ? Fs : Fc;
        _Float16* dst = (sect == 1) ? Kt : Qt;
        const float scale = (sect == 1) ? 1.0f : RLOG2E;
        const float* sb = src + (size_t)b * Cc * HWs;
        {
            int c = t >> 2, x4 = (t & 3) * 4;         // 256 float4 = whole tile
            float4 v = *(const float4*)(sb + (size_t)c * HWs + hw0 + x4);
            T[x4 + 0][c] = (_Float16)(v.x * scale);
            T[x4 + 1][c] = (_Float16)(v.y * scale);
            T[x4 + 2][c] = (_Float16)(v.z * scale);
            T[x4 + 3][c] = (_Float16)(v.w * scale);
        }
        __syncthreads();
        if (t < 128) {
            int row = t >> 3, g = t & 7;
            _Float16* db = dst + (size_t)b * HWs * Cc;
            *(half8*)(db + (size_t)(hw0 + row) * Cc + g * 8) = *(half8*)&T[row][g * 8];
        }
    }
}

// ---- attn: flash, LDS tiles, 64 q/wave (4 groups) ----
__global__ __launch_bounds__(256, 2) void attn_k(const _Float16* __restrict__ Qt,
                                                 const _Float16* __restrict__ Kt,
                                                 const _Float16* __restrict__ Vt,
                                                 _Float16* __restrict__ Opart,
                                                 float2* __restrict__ ml) {
    const int tid  = threadIdx.x;                 // 0..255
    const int w    = tid >> 6;                    // wave 0..3
    const int lane = tid & 63;
    const int quad = lane >> 4;
    const int l15  = lane & 15;
    // block: [split][b][qgroup]
    const int qg = blockIdx.x & 15;               // 16 q-groups of 256
    const int b  = (blockIdx.x >> 4) & 3;
    const int s  = blockIdx.x >> 6;
    const int k0base = s * TPS * 64;
    const int qbase = qg * 256 + w * 64 + l15;    // group g q-row = qbase + g*16

    // xor-swizzled tiles: 16B chunk j of row r stored at chunk j^(r&7)
    __shared__ _Float16 Kl[2][64 * 64];
    __shared__ _Float16 Vl[2][64 * 64];
    __shared__ _Float16 Ps[4][2][16][72];         // per-wave, 2 alternating sets

    const _Float16* Qb = Qt + (size_t)b * HWs * Cc;
    const _Float16* Kb = Kt + (size_t)b * HWs * Cc;
    const _Float16* Vb = Vt + (size_t)b * Cc * HWs;

    // staging role: tids 0..127 stage K, 128..255 stage V; 4 chunks each
    const bool isK  = tid < 128;
    const int  sl   = tid & 127;
    const int  srow = sl >> 3;                    // 0..15 (+16i)
    const int  sjg  = sl & 7;                     // global 16B chunk in row
    const int  ssw  = (sjg ^ (srow & 7)) * 8;     // swizzled chunk offset (halfs)

    // Q B-frags (pre-scaled by log2e in prep): 8 b128 loads
    half8 qf[4][2];
    #pragma unroll
    for (int g = 0; g < 4; ++g) {
        qf[g][0] = *(const half8*)(Qb + (size_t)(qbase + g * 16) * Cc + quad * 8);
        qf[g][1] = *(const half8*)(Qb + (size_t)(qbase + g * 16) * Cc + 32 + quad * 8);
    }

    half8 st[4];
    auto stage_load = [&](int kt) {
        int kk0 = k0base + kt * 64;
        #pragma unroll
        for (int i = 0; i < 4; ++i) {
            int row = srow + 16 * i;
            if (isK) st[i] = *(const half8*)(Kb + (size_t)(kk0 + row) * 64 + sjg * 8);
            else     st[i] = *(const half8*)(Vb + (size_t)row * HWs + kk0 + sjg * 8);
        }
    };
    auto stage_write = [&](int p) {
        #pragma unroll
        for (int i = 0; i < 4; ++i) {
            int row = srow + 16 * i;
            if (isK) *(half8*)&Kl[p][row * 64 + ssw] = st[i];
            else     *(half8*)&Vl[p][row * 64 + ssw] = st[i];
        }
    };

    floatx4 acc[4][4];                            // [g][m]
    #pragma unroll
    for (int g = 0; g < 4; ++g)
        #pragma unroll
        for (int m = 0; m < 4; ++m) acc[g][m] = (floatx4)(0.0f);
    float m_run[4] = {-INFINITY, -INFINITY, -INFINITY, -INFINITY};
    float lsum[4] = {0.0f, 0.0f, 0.0f, 0.0f};

    stage_load(0);
    stage_write(0);
    stage_load(1);
    __syncthreads();

    const int swl = (l15 & 7);
    for (int kt = 0; kt < TPS; ++kt) {
        const int p = kt & 1;
        if (kt + 1 < TPS) stage_write(p ^ 1);
        if (kt + 2 < TPS) stage_load(kt + 2);

        // S^T tiles: stream K A-frags per m (2 b128 live at a time)
        floatx4 sv[4][4];                         // [g][m]
        #pragma unroll
        for (int m = 0; m < 4; ++m) {
            half8 ka0 = *(const half8*)&Kl[p][(m * 16 + l15) * 64 + ((quad ^ swl) * 8)];
            half8 ka1 = *(const half8*)&Kl[p][(m * 16 + l15) * 64 + (((4 + quad) ^ swl) * 8)];
            #pragma unroll
            for (int g = 0; g < 4; ++g) {
                sv[g][m] = __builtin_amdgcn_mfma_f32_16x16x32_f16(ka0, qf[g][0], (floatx4)(0.0f), 0, 0, 0);
                sv[g][m] = __builtin_amdgcn_mfma_f32_16x16x32_f16(ka1, qf[g][1], sv[g][m], 0, 0, 0);
            }
        }

        // V A-frags (issued before softmax, consumed after)
        half8 va[4][2];
        #pragma unroll
        for (int m = 0; m < 4; ++m)
            #pragma unroll
            for (int ks = 0; ks < 2; ++ks)
                va[m][ks] = *(const half8*)&Vl[p][(m * 16 + l15) * 64 + (((ks * 4 + quad) ^ swl) * 8)];

        // softmax per q-group (log2 domain) + PV update
        #pragma unroll
        for (int g = 0; g < 4; ++g) {
            float mx = -INFINITY;
            #pragma unroll
            for (int m = 0; m < 4; ++m)
                #pragma unroll
                for (int r = 0; r < 4; ++r) mx = fmaxf(mx, sv[g][m][r]);
            mx = fmaxf(mx, __shfl_xor(mx, 16));
            mx = fmaxf(mx, __shfl_xor(mx, 32));
            float m_new = fmaxf(m_run[g], mx);
            float alpha = exp2f(m_run[g] - m_new);    // 0 on first tile
            m_run[g] = m_new;
            float part = 0.0f;
            #pragma unroll
            for (int m = 0; m < 4; ++m)
                #pragma unroll
                for (int r = 0; r < 4; ++r) {
                    float e = exp2f(sv[g][m][r] - m_new);
                    sv[g][m][r] = e;
                    part += e;
                }
            lsum[g] = lsum[g] * alpha + part;
            #pragma unroll
            for (int m = 0; m < 4; ++m)
                #pragma unroll
                for (int r = 0; r < 4; ++r) acc[g][m][r] *= alpha;

            // P^T C-layout -> LDS set (g&1) -> B-frags (wave-private)
            #pragma unroll
            for (int m = 0; m < 4; ++m) {
                half4 pp;
                pp[0] = (_Float16)sv[g][m][0]; pp[1] = (_Float16)sv[g][m][1];
                pp[2] = (_Float16)sv[g][m][2]; pp[3] = (_Float16)sv[g][m][3];
                *(half4*)&Ps[w][g & 1][l15][m * 16 + quad * 4] = pp;
            }
            half8 pb0 = *(half8*)&Ps[w][g & 1][l15][quad * 8];
            half8 pb1 = *(half8*)&Ps[w][g & 1][l15][32 + quad * 8];

            #pragma unroll
            for (int m = 0; m < 4; ++m) {
                acc[g][m] = __builtin_amdgcn_mfma_f32_16x16x32_f16(va[m][0], pb0, acc[g][m], 0, 0, 0);
                acc[g][m] = __builtin_amdgcn_mfma_f32_16x16x32_f16(va[m][1], pb1, acc[g][m], 0, 0, 0);
            }
        }

        __syncthreads();                          // one barrier per tile
    }

    // epilogue: quad-reduce row-sums once; write f16 partials + (M,l)
    _Float16* op = Opart + (((size_t)s * Bb + b) * Cc) * HWs;
    #pragma unroll
    for (int g = 0; g < 4; ++g) {
        lsum[g] += __shfl_xor(lsum[g], 16);
        lsum[g] += __shfl_xor(lsum[g], 32);
        int q = qbase + g * 16;
        #pragma unroll
        for (int m = 0; m < 4; ++m)
            #pragma unroll
            for (int r = 0; r < 4; ++r) {
                int c = m * 16 + quad * 4 + r;
                op[(size_t)c * HWs + q] = (_Float16)acc[g][m][r];
            }
        if (quad == 0)
            ml[((size_t)b * HWs + q) * SPLITS + s] = make_float2(m_run[g], lsum[g]);
    }
}

// ---- combine: merge 8 splits (exp2 domain) ----
__global__ __launch_bounds__(256) void combine_k(const _Float16* __restrict__ Opart,
                                                 const float2* __restrict__ ml,
                                                 float* __restrict__ out) {
    int idx = blockIdx.x * 256 + threadIdx.x;     // over 4*64*4096 = 1M
    int q = idx & 4095;
    int c = (idx >> 12) & 63;
    int b = idx >> 18;
    const float2* mlp = ml + ((size_t)b * HWs + q) * SPLITS;
    float2 mls[SPLITS];
    #pragma unroll
    for (int s = 0; s < SPLITS; ++s) mls[s] = mlp[s];
    float M = -INFINITY;
    #pragma unroll
    for (int s = 0; s < SPLITS; ++s) M = fmaxf(M, mls[s].x);
    float l = 0.0f, wgt[SPLITS];
    #pragma unroll
    for (int s = 0; s < SPLITS; ++s) {
        wgt[s] = exp2f(mls[s].x - M);
        l += wgt[s] * mls[s].y;
    }
    float o = 0.0f;
    #pragma unroll
    for (int s = 0; s < SPLITS; ++s)
        o += wgt[s] * (float)Opart[(((size_t)s * Bb + b) * Cc + c) * HWs + q];
    out[((size_t)b * 2 * Cc + Cc + c) * HWs + q] = o / l;
}

extern "C" void kernel_launch(void* const* d_in, const int* in_sizes, int n_in,
                              void* d_out, int out_size, void* d_ws, size_t ws_size,
                              hipStream_t stream) {
    const float* content   = (const float*)d_in[0];
    const float* content_s = (const float*)d_in[1];
    const float* style     = (const float*)d_in[2];
    float* out = (float*)d_out;

    _Float16* Qt = (_Float16*)d_ws;                           // [4][4096][64] f16 (2 MB)
    _Float16* Kt = Qt + (size_t)Bb * HWs * Cc;                // [4][4096][64] f16 (2 MB)
    _Float16* Vt = Kt + (size_t)Bb * HWs * Cc;                // [4][64][4096] f16 (2 MB)
    _Float16* Opart = Vt + (size_t)Bb * Cc * HWs;             // [8][4][64][4096] f16 (16.8 MB)
    float2*   ml = (float2*)(Opart + (size_t)SPLITS * Bb * Cc * HWs);  // [4][4096][8] (1 MB)

    prep_k<<<dim3(3072), dim3(256), 0, stream>>>(content, content, content_s, style,
                                                 out, Qt, Kt, Vt);
    attn_k<<<dim3(SPLITS * Bb * 16), dim3(256), 0, stream>>>(Qt, Kt, Vt, Opart, ml);
    combine_k<<<dim3(4096), dim3(256), 0, stream>>>(Opart, ml, out);
}

// Round 8
// 113.991 us; speedup vs baseline: 1.0325x; 1.0325x over previous
//
#include <hip/hip_runtime.h>
#include <math.h>

// SANet attention: MFMA flash, LDS-staged K/V (xor-swizzled), 64 q-rows/wave
// processed as 2 streamed group-pairs, split-K(8), f16 partials.
// b=4, c=64, HW=4096, fp32 in/out.
// out[b,0:64,:] = content ; out[b,64:128,q] = sum_k Fst[:,k] softmax_k(Fc[:,q].Fs[:,k])
//
// R7 post-mortem: sv[4][4] live across all groups -> ~270 VGPR > 256 cap ->
// spills. R8: stream 2 group-pairs (sv[2][4]); K A-frags re-read per pair
// (+8 b128/tile, cheap); live set ~220. Prep reverted to 2048 blocks (no Qt;
// Q direct from fp32 Fc, one-time). ~47us of dur_us is the harness's 268MB
// ws-poison fill (uncontrollable floor).
//
// mfma_f32_16x16x32_f16: A[m=lane&15][k=quad*8+j], B[k=quad*8+j][n=lane&15],
// D[m=quad*4+reg][n=lane&15]  (quad = lane>>4).
// S-mfma computes S^T tile (m=k_key, n=q); PV computes O^T (m=c, n=q).

#define Bb 4
#define Cc 64
#define HWs 4096
#define SPLITS 8
#define TPS 8                   // tiles per split: 512 keys / 64
#define RLOG2E 1.44269504088896340736f

typedef _Float16 half8 __attribute__((ext_vector_type(8)));
typedef _Float16 half4 __attribute__((ext_vector_type(4)));
typedef float floatx4 __attribute__((ext_vector_type(4)));

// ---- prep: content copy + Vt convert + Kt transpose ----
__global__ __launch_bounds__(256) void prep_k(const float* __restrict__ content,
                                              const float* __restrict__ Fs,
                                              const float* __restrict__ Fst,
                                              float* __restrict__ out,
                                              _Float16* __restrict__ Kt,
                                              _Float16* __restrict__ Vt) {
    const int bid = blockIdx.x;
    const int t = threadIdx.x;
    if (bid < 1024) {
        // content copy (float4) + V f16 convert (same linear layout)
        int i4 = bid * 256 + t;                       // 0..262143
        const float4* c4 = (const float4*)content;
        const float4* v4 = (const float4*)Fst;
        float4* o4 = (float4*)out;
        int b = i4 >> 16, rem = i4 & 65535;
        o4[(size_t)b * 131072 + rem] = c4[i4];        // out batch stride 2*64*4096 f32
        float4 v = v4[i4];
        half4 h;
        h[0] = (_Float16)v.x; h[1] = (_Float16)v.y;
        h[2] = (_Float16)v.z; h[3] = (_Float16)v.w;
        *(half4*)(Vt + (size_t)i4 * 4) = h;
    } else {
        // transpose+convert one 16hw x 64c tile of Fs -> Kt[b][k][c]
        __shared__ _Float16 T[16][72];
        int e = bid - 1024;                           // 0..1023
        int b = e >> 8;
        int hw0 = (e & 255) * 16;
        const float* sb = Fs + (size_t)b * Cc * HWs;
        {
            int c = t >> 2, x4 = (t & 3) * 4;         // 256 float4 = whole tile
            float4 v = *(const float4*)(sb + (size_t)c * HWs + hw0 + x4);
            T[x4 + 0][c] = (_Float16)v.x;
            T[x4 + 1][c] = (_Float16)v.y;
            T[x4 + 2][c] = (_Float16)v.z;
            T[x4 + 3][c] = (_Float16)v.w;
        }
        __syncthreads();
        if (t < 128) {
            int row = t >> 3, g = t & 7;
            _Float16* db = Kt + (size_t)b * HWs * Cc;
            *(half8*)(db + (size_t)(hw0 + row) * Cc + g * 8) = *(half8*)&T[row][g * 8];
        }
    }
}

// ---- attn: flash, LDS tiles, 64 q/wave as 2 streamed pairs ----
__global__ __launch_bounds__(256, 2) void attn_k(const float* __restrict__ Fc,
                                                 const _Float16* __restrict__ Kt,
                                                 const _Float16* __restrict__ Vt,
                                                 _Float16* __restrict__ Opart,
                                                 float2* __restrict__ ml) {
    const int tid  = threadIdx.x;                 // 0..255
    const int w    = tid >> 6;                    // wave 0..3
    const int lane = tid & 63;
    const int quad = lane >> 4;
    const int l15  = lane & 15;
    // block: [split][b][qgroup]
    const int qg = blockIdx.x & 15;               // 16 q-groups of 256
    const int b  = (blockIdx.x >> 4) & 3;
    const int s  = blockIdx.x >> 6;
    const int k0base = s * TPS * 64;
    const int qbase = qg * 256 + w * 64 + l15;    // group g q-row = qbase + g*16

    // xor-swizzled tiles: 16B chunk j of row r stored at chunk j^(r&7)
    __shared__ _Float16 Kl[2][64 * 64];
    __shared__ _Float16 Vl[2][64 * 64];
    __shared__ _Float16 Ps[4][2][16][72];         // per-wave, 2 alternating sets

    const float*    Fcb = Fc + (size_t)b * Cc * HWs;
    const _Float16* Kb  = Kt + (size_t)b * HWs * Cc;
    const _Float16* Vb  = Vt + (size_t)b * Cc * HWs;

    // staging role: tids 0..127 stage K, 128..255 stage V; 4 chunks each
    const bool isK  = tid < 128;
    const int  sl   = tid & 127;
    const int  srow = sl >> 3;                    // 0..15 (+16i)
    const int  sjg  = sl & 7;                     // global 16B chunk in row
    const int  ssw  = (sjg ^ (srow & 7)) * 8;     // swizzled chunk offset (halfs)

    // Q B-frags from fp32 Fc, pre-scaled by log2e (one-time strided loads)
    half8 qf[4][2];
    #pragma unroll
    for (int g = 0; g < 4; ++g)
        #pragma unroll
        for (int j = 0; j < 8; ++j) {
            qf[g][0][j] = (_Float16)(Fcb[(size_t)(quad * 8 + j) * HWs + qbase + g * 16] * RLOG2E);
            qf[g][1][j] = (_Float16)(Fcb[(size_t)(32 + quad * 8 + j) * HWs + qbase + g * 16] * RLOG2E);
        }

    half8 st[4];
    auto stage_load = [&](int kt) {
        int kk0 = k0base + kt * 64;
        #pragma unroll
        for (int i = 0; i < 4; ++i) {
            int row = srow + 16 * i;
            if (isK) st[i] = *(const half8*)(Kb + (size_t)(kk0 + row) * 64 + sjg * 8);
            else     st[i] = *(const half8*)(Vb + (size_t)row * HWs + kk0 + sjg * 8);
        }
    };
    auto stage_write = [&](int p) {
        #pragma unroll
        for (int i = 0; i < 4; ++i) {
            int row = srow + 16 * i;
            if (isK) *(half8*)&Kl[p][row * 64 + ssw] = st[i];
            else     *(half8*)&Vl[p][row * 64 + ssw] = st[i];
        }
    };

    floatx4 acc[4][4];                            // [g][m]
    #pragma unroll
    for (int g = 0; g < 4; ++g)
        #pragma unroll
        for (int m = 0; m < 4; ++m) acc[g][m] = (floatx4)(0.0f);
    float m_run[4] = {-INFINITY, -INFINITY, -INFINITY, -INFINITY};
    float lsum[4] = {0.0f, 0.0f, 0.0f, 0.0f};

    stage_load(0);
    stage_write(0);
    stage_load(1);
    __syncthreads();

    const int swl = (l15 & 7);
    for (int kt = 0; kt < TPS; ++kt) {
        const int p = kt & 1;
        if (kt + 1 < TPS) stage_write(p ^ 1);
        if (kt + 2 < TPS) stage_load(kt + 2);

        // V A-frags (loaded once, live across both group-pairs)
        half8 va[4][2];
        #pragma unroll
        for (int m = 0; m < 4; ++m)
            #pragma unroll
            for (int ks = 0; ks < 2; ++ks)
                va[m][ks] = *(const half8*)&Vl[p][(m * 16 + l15) * 64 + (((ks * 4 + quad) ^ swl) * 8)];

        // two streamed group-pairs: sv[2][4] live (32 regs), ka re-read per pair
        #pragma unroll
        for (int h = 0; h < 2; ++h) {
            floatx4 sv[2][4];
            #pragma unroll
            for (int m = 0; m < 4; ++m) {
                half8 ka0 = *(const half8*)&Kl[p][(m * 16 + l15) * 64 + ((quad ^ swl) * 8)];
                half8 ka1 = *(const half8*)&Kl[p][(m * 16 + l15) * 64 + (((4 + quad) ^ swl) * 8)];
                #pragma unroll
                for (int u = 0; u < 2; ++u) {
                    const int g = h * 2 + u;
                    sv[u][m] = __builtin_amdgcn_mfma_f32_16x16x32_f16(ka0, qf[g][0], (floatx4)(0.0f), 0, 0, 0);
                    sv[u][m] = __builtin_amdgcn_mfma_f32_16x16x32_f16(ka1, qf[g][1], sv[u][m], 0, 0, 0);
                }
            }

            #pragma unroll
            for (int u = 0; u < 2; ++u) {
                const int g = h * 2 + u;
                float mx = -INFINITY;
                #pragma unroll
                for (int m = 0; m < 4; ++m)
                    #pragma unroll
                    for (int r = 0; r < 4; ++r) mx = fmaxf(mx, sv[u][m][r]);
                mx = fmaxf(mx, __shfl_xor(mx, 16));
                mx = fmaxf(mx, __shfl_xor(mx, 32));
                float m_new = fmaxf(m_run[g], mx);
                float alpha = exp2f(m_run[g] - m_new);    // 0 on first tile
                m_run[g] = m_new;
                float part = 0.0f;
                #pragma unroll
                for (int m = 0; m < 4; ++m)
                    #pragma unroll
                    for (int r = 0; r < 4; ++r) {
                        float e = exp2f(sv[u][m][r] - m_new);
                        sv[u][m][r] = e;
                        part += e;
                    }
                lsum[g] = lsum[g] * alpha + part;
                #pragma unroll
                for (int m = 0; m < 4; ++m)
                    #pragma unroll
                    for (int r = 0; r < 4; ++r) acc[g][m][r] *= alpha;

                // P^T C-layout -> LDS set u -> B-frags (wave-private)
                #pragma unroll
                for (int m = 0; m < 4; ++m) {
                    half4 pp;
                    pp[0] = (_Float16)sv[u][m][0]; pp[1] = (_Float16)sv[u][m][1];
                    pp[2] = (_Float16)sv[u][m][2]; pp[3] = (_Float16)sv[u][m][3];
                    *(half4*)&Ps[w][u][l15][m * 16 + quad * 4] = pp;
                }
                half8 pb0 = *(half8*)&Ps[w][u][l15][quad * 8];
                half8 pb1 = *(half8*)&Ps[w][u][l15][32 + quad * 8];

                #pragma unroll
                for (int m = 0; m < 4; ++m) {
                    acc[g][m] = __builtin_amdgcn_mfma_f32_16x16x32_f16(va[m][0], pb0, acc[g][m], 0, 0, 0);
                    acc[g][m] = __builtin_amdgcn_mfma_f32_16x16x32_f16(va[m][1], pb1, acc[g][m], 0, 0, 0);
                }
            }
        }

        __syncthreads();                          // one barrier per tile
    }

    // epilogue: quad-reduce row-sums once; write f16 partials + (M,l)
    _Float16* op = Opart + (((size_t)s * Bb + b) * Cc) * HWs;
    #pragma unroll
    for (int g = 0; g < 4; ++g) {
        lsum[g] += __shfl_xor(lsum[g], 16);
        lsum[g] += __shfl_xor(lsum[g], 32);
        int q = qbase + g * 16;
        #pragma unroll
        for (int m = 0; m < 4; ++m)
            #pragma unroll
            for (int r = 0; r < 4; ++r) {
                int c = m * 16 + quad * 4 + r;
                op[(size_t)c * HWs + q] = (_Float16)acc[g][m][r];
            }
        if (quad == 0)
            ml[((size_t)b * HWs + q) * SPLITS + s] = make_float2(m_run[g], lsum[g]);
    }
}

// ---- combine: merge 8 splits (exp2 domain) ----
__global__ __launch_bounds__(256) void combine_k(const _Float16* __restrict__ Opart,
                                                 const float2* __restrict__ ml,
                                                 float* __restrict__ out) {
    int idx = blockIdx.x * 256 + threadIdx.x;     // over 4*64*4096 = 1M
    int q = idx & 4095;
    int c = (idx >> 12) & 63;
    int b = idx >> 18;
    const float2* mlp = ml + ((size_t)b * HWs + q) * SPLITS;
    float2 mls[SPLITS];
    #pragma unroll
    for (int s = 0; s < SPLITS; ++s) mls[s] = mlp[s];
    float M = -INFINITY;
    #pragma unroll
    for (int s = 0; s < SPLITS; ++s) M = fmaxf(M, mls[s].x);
    float l = 0.0f, wgt[SPLITS];
    #pragma unroll
    for (int s = 0; s < SPLITS; ++s) {
        wgt[s] = exp2f(mls[s].x - M);
        l += wgt[s] * mls[s].y;
    }
    float o = 0.0f;
    #pragma unroll
    for (int s = 0; s < SPLITS; ++s)
        o += wgt[s] * (float)Opart[(((size_t)s * Bb + b) * Cc + c) * HWs + q];
    out[((size_t)b * 2 * Cc + Cc + c) * HWs + q] = o / l;
}

extern "C" void kernel_launch(void* const* d_in, const int* in_sizes, int n_in,
                              void* d_out, int out_size, void* d_ws, size_t ws_size,
                              hipStream_t stream) {
    const float* content   = (const float*)d_in[0];
    const float* content_s = (const float*)d_in[1];
    const float* style     = (const float*)d_in[2];
    float* out = (float*)d_out;

    _Float16* Kt = (_Float16*)d_ws;                           // [4][4096][64] f16 (2 MB)
    _Float16* Vt = Kt + (size_t)Bb * HWs * Cc;                // [4][64][4096] f16 (2 MB)
    _Float16* Opart = Vt + (size_t)Bb * Cc * HWs;             // [8][4][64][4096] f16 (16.8 MB)
    float2*   ml = (float2*)(Opart + (size_t)SPLITS * Bb * Cc * HWs);  // [4][4096][8] (1 MB)

    prep_k<<<dim3(2048), dim3(256), 0, stream>>>(content, content_s, style, out, Kt, Vt);
    attn_k<<<dim3(SPLITS * Bb * 16), dim3(256), 0, stream>>>(content, Kt, Vt, Opart, ml);
    combine_k<<<dim3(4096), dim3(256), 0, stream>>>(Opart, ml, out);
}